// Round 13
// baseline (552.823 us; speedup 1.0000x reference)
//
#include <hip/hip_runtime.h>
#include <cmath>

// Problem constants: V=50000, E=300, H=512, L=6, N=8192, K=4
#define VSZ  50000
#define EDIM 300
#define EPAD 320      // E padded to multiple of 32
#define HDIM 512
#define LVLS 6
#define NN   8192
#define KCH  4

// MFMA GEMM tile: 128x128 block, BK=32, 4 waves of 64x64 (4x4 grid of 16x16x32 MFMA)
#define BM 128
#define BN 128
#define BK 32

typedef __attribute__((ext_vector_type(8))) short bf16x8;
typedef __attribute__((ext_vector_type(8))) unsigned short us8;
typedef __attribute__((ext_vector_type(4))) float f32x4;

__device__ __forceinline__ float sigf(float x) { return 1.0f / (1.0f + expf(-x)); }

// fast tanh: 2*sigmoid(2x)-1 — one v_exp + rcp + fma, saturates correctly
// (expf(+inf)->inf -> sig->0 -> -1; expf(-inf)->0 -> sig->1 -> +1).
// abs err <= ~1e-6, far below the bf16 rounding already in the pipeline.
__device__ __forceinline__ float ftanh(float x) {
    return 2.0f * sigf(2.0f * x) - 1.0f;
}

__device__ __forceinline__ unsigned short f2bf(float f) {
    unsigned u = __float_as_uint(f);
    u += 0x7FFF + ((u >> 16) & 1);           // RNE
    return (unsigned short)(u >> 16);
}
__device__ __forceinline__ float bf2f(unsigned short h) {
    return __uint_as_float(((unsigned)h) << 16);
}

// HW packed f32->bf16 (RNE), 2 values per instruction
__device__ __forceinline__ unsigned cvt_pk_bf16(float lo, float hi) {
    unsigned r;
    asm("v_cvt_pk_bf16_f32 %0, %1, %2" : "=v"(r) : "v"(lo), "v"(hi));
    return r;
}

// ---- merged gather+convert for BOTH batches (6N rows):
// rows 0..3N-1  (batch A, levels 3..5): vix row = 3N + r
// rows 3N..6N-1 (batch B, levels 0..2): vix row = r - 3N
// out[r][e] = bf16(embed[vix][e] * tmask[vix_row]); e>=EDIM -> 0.
// AbatB is contiguous after AbatA, so a single out base covers both.
__global__ __launch_bounds__(256) void gconv2_k(
    const float* __restrict__ embed, const int* __restrict__ vix,
    const float* __restrict__ tmask, unsigned short* __restrict__ out)
{
    int t  = blockIdx.x * 256 + threadIdx.x;     // 6*NN*40 total
    int r  = t / (EPAD / 8);
    int j8 = (t - r * (EPAD / 8)) * 8;
    int rr = (r < 3 * NN) ? (3 * NN + r) : (r - 3 * NN);
    float m = tmask[rr];
    int   v = vix[rr];
    const float* src = embed + (size_t)v * EDIM + j8;
    us8 o;
    if (j8 + 8 <= EDIM) {
        float4 a = *(const float4*)(src);
        float4 b = *(const float4*)(src + 4);
        const float xs[8] = {a.x, a.y, a.z, a.w, b.x, b.y, b.z, b.w};
#pragma unroll
        for (int j = 0; j < 8; ++j) o[j] = f2bf(xs[j] * m);
    } else {
#pragma unroll
        for (int j = 0; j < 8; ++j) {
            float x = (j8 + j < EDIM) ? src[j] * m : 0.0f;
            o[j] = f2bf(x);
        }
    }
    *(us8*)(out + (size_t)r * EPAD + j8) = o;
}

// ---- merged transpose+convert for all 4 weights (one launch):
// R0: WtALL[0..3H*EPAD)   <- W_iou^T  (k<EDIM real, pad to EPAD)
// R1: WtALL[3H*EPAD..)    <- W_f^T
// R2: UtALL[0..3H*H)      <- U_iou^T  (no pad, Ksp=H)
// R3: UtALL[3H*H..)       <- U_f^T
#define WCS0 (3 * HDIM * EPAD)
#define WCS1 (HDIM * EPAD)
#define WCS2 (3 * HDIM * HDIM)
#define WCS3 (HDIM * HDIM)
__global__ __launch_bounds__(256) void wconvall_k(
    const float* __restrict__ W_iou, const float* __restrict__ W_f,
    const float* __restrict__ U_iou, const float* __restrict__ U_f,
    unsigned short* __restrict__ WtALL, unsigned short* __restrict__ UtALL)
{
    int t = blockIdx.x * 256 + threadIdx.x;     // WCS0+WCS1+WCS2+WCS3 total
    if (t < WCS0) {
        int k = t % EPAD, n = t / EPAD;
        WtALL[t] = (k < EDIM) ? f2bf(W_iou[(size_t)k * (3 * HDIM) + n]) : (unsigned short)0;
    } else if (t < WCS0 + WCS1) {
        int u = t - WCS0;
        int k = u % EPAD, n = u / EPAD;
        WtALL[t] = (k < EDIM) ? f2bf(W_f[(size_t)k * HDIM + n]) : (unsigned short)0;
    } else if (t < WCS0 + WCS1 + WCS2) {
        int u = t - WCS0 - WCS1;
        int k = u % HDIM, n = u / HDIM;
        UtALL[u] = f2bf(U_iou[(size_t)k * (3 * HDIM) + n]);
    } else {
        int u = t - WCS0 - WCS1 - WCS2;
        int k = u % HDIM, n = u / HDIM;
        UtALL[WCS2 + u] = f2bf(U_f[(size_t)k * HDIM + n]);
    }
}

#define GLL(src, dst)                                                        \
    __builtin_amdgcn_global_load_lds(                                        \
        (const __attribute__((address_space(1))) unsigned int*)(src), (dst), 16, 0, 0)

// Dense bf16 GEMM C[M,N] = A[M,Ks] @ Bt[N,Ks]^T
// EPI: 0 = C = bf16(acc); 1 = C = bf16(acc + (col<1536 ? b_iou[col] : b_f[col-1536]))
// Each block processes NCHUNK consecutive N-tiles.
//   Measured (r6-r12): embed GEMM prefers larger NCHUNK (r6 58.4 @2 vs r7
//   62.4 @1); r13 tries NCHUNK=4 @(4,192) = 768 blocks = exactly 3/CU =
//   full co-residency, no second dispatch round. Z-GEMM best at
//   (16,64)/NCHUNK=1. Direct-store epilogue REGRESSED (r8); distance-3/64KB
//   REGRESSED (r10). Body is the r9/r11-measured-best: 3-stage, dist 2, 48KB.
// XCD-aware swizzle: linear block id P -> XCD g=P%8 owns a contiguous band of
// M-tiles with ALL n-groups, so A-band + B panels are L2-resident per XCD.
// Requires gridDim.y % 8 == 0.
// K-loop (T3+T4, 3-stage): triple-buffer rotation, prefetch distance 2,
// ONE barrier per K-step:
//   per interval i: STAGE(k[i+2] -> buf[(i+2)%3]); COMPUTE(buf[i%3]);
//                   s_waitcnt vmcnt(4); s_barrier.
// Safety: waves all sit between barrier i-1 and i, so the staged buffer
// (== buf[i-1]) was finished by every wave before barrier i-1. The counted
// wait covers loads issued a FULL compute interval ago (cheap), and the
// prefetch stays in flight across the barrier (never vmcnt(0) mid-loop).
// LDS: 3 x 16 KB buffers = 48 KB (3 blocks/CU cap); XOR-swizzled 16B
// granules via global_load_lds (wave-uniform dest).
// Epilogue: LDS-transposed (32x128 f32 stripes in buffer 0, XOR-granule
// swizzle), v_cvt_pk_bf16_f32 conversion, coalesced dwordx4 stores.
template <int EPI, int NCHUNK>
__global__ __launch_bounds__(256) void mgemm_k(
    const unsigned short* __restrict__ Ab,
    const unsigned short* __restrict__ Bt,
    const float* __restrict__ b_iou, const float* __restrict__ b_f,
    unsigned short* __restrict__ C, int ldc, int Ks)
{
    // 3 buffers of (A 4096 shorts | B 4096 shorts) = 48 KB total
    __shared__ __align__(16) unsigned short smem[6 * BM * BK];

    const int tid  = threadIdx.x;
    const int wave = tid >> 6;
    const int lane = tid & 63;
    const int quad = lane >> 4;
    const int mcol = lane & 15;
    const int wm   = (wave >> 1) * 64;
    const int wn   = (wave & 1) * 64;
    const int band = wave >> 1;

    // ---- XCD swizzle (bijective; gridDim.y % 8 == 0) ----
    const int GX   = gridDim.x;                 // n-groups
    const int P    = blockIdx.x + GX * blockIdx.y;
    const int g    = P & 7;
    const int s    = P >> 3;
    const int mper = gridDim.y >> 3;
    const int sdiv = s / GX;
    const int my_mt = g * mper + sdiv;          // m-tile
    const int my_ng = s - sdiv * GX;            // n-group
    const int tile_m = my_mt * BM;

    // staging: thread handles chunks c0=tid, c1=tid+256 (identity LDS placement)
    const int r0  = tid >> 2;
    const int kg0 = (tid & 3) ^ ((r0 >> 1) & 3);
    const int cc1 = tid + 256;
    const int r1  = cc1 >> 2;
    const int kg1 = (cc1 & 3) ^ ((r1 >> 1) & 3);

    const unsigned short* asrc0 = Ab + (size_t)(tile_m + r0) * Ks + kg0 * 8;
    const unsigned short* asrc1 = Ab + (size_t)(tile_m + r1) * Ks + kg1 * 8;

    typedef __attribute__((address_space(3))) unsigned int lds_u32;

    // epilogue views/indices (eb = buffer-0 region, 16 KB)
    float* eb = reinterpret_cast<float*>(smem);          // 32x128 f32
    const int erl = tid >> 3;                            // 0..31 (stripe row)
    const int ecg = tid & 7;                             // 0..7  (16-col group)

// stage K-slice kk into buffer at short-offset bo (A at bo, B at bo+4096)
#define STAGE3(kk, bo)                                                       \
    {                                                                        \
        GLL(asrc0 + (kk), (lds_u32*)(smem + (bo) + wave * 512));             \
        GLL(asrc1 + (kk), (lds_u32*)(smem + (bo) + 2048 + wave * 512));      \
        GLL(bsrc0 + (kk), (lds_u32*)(smem + (bo) + 4096 + wave * 512));      \
        GLL(bsrc1 + (kk), (lds_u32*)(smem + (bo) + 6144 + wave * 512));      \
    }
#define WAITV4  asm volatile("s_waitcnt vmcnt(4)" ::: "memory")
#define WAITV0  asm volatile("s_waitcnt vmcnt(0)" ::: "memory")
#define BAR     __builtin_amdgcn_s_barrier()

#define COMPUTE(bo)                                                         \
    {                                                                       \
        const unsigned short* AS = smem + (bo);                             \
        const unsigned short* BS = smem + (bo) + 4096;                      \
        bf16x8 afr[4], bfr[4];                                              \
        _Pragma("unroll")                                                   \
        for (int mt = 0; mt < 4; ++mt) {                                    \
            int rw = wm + mt * 16 + mcol;                                   \
            int p  = rw * 4 + (quad ^ ((rw >> 1) & 3));                     \
            afr[mt] = *(const bf16x8*)(AS + p * 8);                         \
        }                                                                   \
        _Pragma("unroll")                                                   \
        for (int nt = 0; nt < 4; ++nt) {                                    \
            int rw = wn + nt * 16 + mcol;                                   \
            int p  = rw * 4 + (quad ^ ((rw >> 1) & 3));                     \
            bfr[nt] = *(const bf16x8*)(BS + p * 8);                         \
        }                                                                   \
        _Pragma("unroll")                                                   \
        for (int mt = 0; mt < 4; ++mt)                                      \
            _Pragma("unroll")                                               \
            for (int nt = 0; nt < 4; ++nt)                                  \
                acc[mt][nt] = __builtin_amdgcn_mfma_f32_16x16x32_bf16(      \
                    afr[mt], bfr[nt], acc[mt][nt], 0, 0, 0);                \
    }

    for (int nc = 0; nc < NCHUNK; ++nc) {
        const int tile_n = (my_ng * NCHUNK + nc) * BN;
        const unsigned short* bsrc0 = Bt + (size_t)(tile_n + r0) * Ks + kg0 * 8;
        const unsigned short* bsrc1 = Bt + (size_t)(tile_n + r1) * Ks + kg1 * 8;

        f32x4 acc[4][4] = {};
        const int nsteps = Ks / BK;              // 10 or 16

        // rotating buffer offsets (shorts): 16 KB apart
        int bo0 = 0, bo1 = 8192, bo2 = 16384;

        // prologue: fill buf0, buf1; wait buf0 only
        STAGE3(0, bo0);
        STAGE3(BK, bo1);
        WAITV4;
        BAR;

        for (int st = 0; st < nsteps; ++st) {
            const bool pf = (st + 2 < nsteps);
            if (pf) STAGE3((st + 2) * BK, bo2);
            COMPUTE(bo0);
            if (pf) { WAITV4; } else { WAITV0; }
            BAR;
            int t0 = bo0; bo0 = bo1; bo1 = bo2; bo2 = t0;
        }

        // ---- epilogue: 4 stripes of 32 rows x 128 cols f32 through LDS ----
        // writer: value acc[mt][nt][rr] is logical (r = band*16+quad*4+rr,
        //         c = wn+nt*16+mcol); phys granule = (c>>2) ^ (r&7).
        // reader: thread handles row erl, cols ecg*16..+15 -> 2 dwordx4 stores.
#pragma unroll
        for (int mt = 0; mt < 4; ++mt) {
            const int rbase = band * 16 + quad * 4;
#pragma unroll
            for (int nt = 0; nt < 4; ++nt) {
                const int cb = wn + nt * 16 + mcol;
                const int gq = cb >> 2;
                const int cl = cb & 3;
#pragma unroll
                for (int rr = 0; rr < 4; ++rr) {
                    const int r = rbase + rr;
                    eb[r * 128 + ((gq ^ (r & 7)) << 2) + cl] = acc[mt][nt][rr];
                }
            }
            __syncthreads();

            const int grow = tile_m + (erl >> 4) * 64 + mt * 16 + (erl & 15);
            const int gcol = tile_n + ecg * 16;
            float v[16];
#pragma unroll
            for (int sxt = 0; sxt < 4; ++sxt) {
                const int pg = (ecg * 4 + sxt) ^ (erl & 7);
                f32x4 q = *(const f32x4*)&eb[erl * 128 + pg * 4];
                v[sxt * 4 + 0] = q[0]; v[sxt * 4 + 1] = q[1];
                v[sxt * 4 + 2] = q[2]; v[sxt * 4 + 3] = q[3];
            }
            if (EPI == 1) {
                const float* bp = (gcol < 3 * HDIM) ? (b_iou + gcol)
                                                    : (b_f + gcol - 3 * HDIM);
                float4 b0 = *(const float4*)(bp);
                float4 b1 = *(const float4*)(bp + 4);
                float4 b2 = *(const float4*)(bp + 8);
                float4 b3 = *(const float4*)(bp + 12);
                const float bb[16] = {b0.x, b0.y, b0.z, b0.w, b1.x, b1.y, b1.z, b1.w,
                                      b2.x, b2.y, b2.z, b2.w, b3.x, b3.y, b3.z, b3.w};
#pragma unroll
                for (int j = 0; j < 16; ++j) v[j] += bb[j];
            }
            unsigned pw[8];
#pragma unroll
            for (int j = 0; j < 8; ++j) pw[j] = cvt_pk_bf16(v[2 * j], v[2 * j + 1]);
            unsigned short* cp = C + (size_t)grow * ldc + gcol;
            *(uint4*)(cp)     = make_uint4(pw[0], pw[1], pw[2], pw[3]);
            *(uint4*)(cp + 8) = make_uint4(pw[4], pw[5], pw[6], pw[7]);
            __syncthreads();
        }
    }
#undef STAGE3
#undef WAITV4
#undef WAITV0
#undef BAR
#undef COMPUTE
}

// fused child-sum + fc + gates (non-leaf).
// iouxW row: bf16 [i|o|u|xwf+bf] (2048). Z row: bf16 [h@U_iou (1536) | h@U_f (512)].
//   ia = i + sum_k m_k * Zi[c_k] ; (same o,u) ; fc = sum_k sigf(xw + m_k*Zf[c_k]) * m_k * c_prev[c_k]
//   c = sigf(ia)*tanh(ua) + fc ; h = sigf(oa)*tanh(c)
// MASK-SKIP (r12, measured -21us): n = t>>6 is WAVE-UNIFORM, so `if (m!=0)`
// is a uniform branch — skipping masked children (~25%) eliminates their
// gathers + VALU exactly, no divergence.
// ftanh (r13): tanhf -> 2*sigmoid(2x)-1 (ocml tanhf is a branchy ~20-inst
// chain; this is 1 exp + rcp + fma).
// LAST: write h f32 to h_out only; else write c_new f32 + hb_new bf16.
template <bool LAST>
__global__ __launch_bounds__(256) void gatefc_k(
    const unsigned short* __restrict__ iouxW, const unsigned short* __restrict__ Z,
    const int* __restrict__ cidx, const float* __restrict__ cmask,
    const float* __restrict__ c_prev,
    float* __restrict__ c_new, unsigned short* __restrict__ hb_new,
    float* __restrict__ h_out)
{
    int t  = blockIdx.x * 256 + threadIdx.x;   // NN*HDIM/8 threads
    int n  = t >> 6;
    int j8 = (t & 63) << 3;
    const unsigned short* xr = iouxW + (size_t)n * 4 * HDIM + j8;
    us8 xi = *(const us8*)xr;
    us8 xo = *(const us8*)(xr + HDIM);
    us8 xu = *(const us8*)(xr + 2 * HDIM);
    us8 xf = *(const us8*)(xr + 3 * HDIM);
    float ia[8], oa[8], ua[8], xw[8], fc[8];
#pragma unroll
    for (int j = 0; j < 8; ++j) {
        ia[j] = bf2f(xi[j]); oa[j] = bf2f(xo[j]);
        ua[j] = bf2f(xu[j]); xw[j] = bf2f(xf[j]);
        fc[j] = 0.0f;
    }
    int4   ci = *(const int4*)&cidx[n * KCH];
    float4 cm = *(const float4*)&cmask[n * KCH];
    const int   cia[4] = {ci.x, ci.y, ci.z, ci.w};
    const float cma[4] = {cm.x, cm.y, cm.z, cm.w};
#pragma unroll
    for (int k = 0; k < KCH; ++k) {
        const float m = cma[k];
        if (m != 0.0f) {                       // wave-uniform branch
            const unsigned short* zr = Z + (size_t)cia[k] * 4 * HDIM + j8;
            us8 zi = *(const us8*)zr;
            us8 zo = *(const us8*)(zr + HDIM);
            us8 zu = *(const us8*)(zr + 2 * HDIM);
            us8 zf = *(const us8*)(zr + 3 * HDIM);
            const float* cpr = c_prev + (size_t)cia[k] * HDIM + j8;
            float4 ca = *(const float4*)cpr;
            float4 cb = *(const float4*)(cpr + 4);
            const float cp[8] = {ca.x, ca.y, ca.z, ca.w, cb.x, cb.y, cb.z, cb.w};
#pragma unroll
            for (int j = 0; j < 8; ++j) {
                ia[j] += m * bf2f(zi[j]);
                oa[j] += m * bf2f(zo[j]);
                ua[j] += m * bf2f(zu[j]);
                fc[j] += sigf(xw[j] + m * bf2f(zf[j])) * m * cp[j];
            }
        }
    }
    float cv[8], hv[8];
#pragma unroll
    for (int j = 0; j < 8; ++j) {
        cv[j] = sigf(ia[j]) * ftanh(ua[j]) + fc[j];
        hv[j] = sigf(oa[j]) * ftanh(cv[j]);
    }
    if (LAST) {
        float4 h0 = make_float4(hv[0], hv[1], hv[2], hv[3]);
        float4 h1 = make_float4(hv[4], hv[5], hv[6], hv[7]);
        *(float4*)(h_out + (size_t)n * HDIM + j8)     = h0;
        *(float4*)(h_out + (size_t)n * HDIM + j8 + 4) = h1;
    } else {
        float4 c0v = make_float4(cv[0], cv[1], cv[2], cv[3]);
        float4 c1v = make_float4(cv[4], cv[5], cv[6], cv[7]);
        *(float4*)(c_new + (size_t)n * HDIM + j8)     = c0v;
        *(float4*)(c_new + (size_t)n * HDIM + j8 + 4) = c1v;
        us8 hb;
#pragma unroll
        for (int j = 0; j < 8; ++j) hb[j] = f2bf(hv[j]);
        *(us8*)(hb_new + (size_t)n * HDIM + j8) = hb;
    }
}

// leaf: fc = 0, no children
__global__ __launch_bounds__(256) void gateleaf_k(
    const unsigned short* __restrict__ iouxW,
    float* __restrict__ c_new, unsigned short* __restrict__ hb_new)
{
    int t  = blockIdx.x * 256 + threadIdx.x;
    int n  = t >> 6;
    int j8 = (t & 63) << 3;
    const unsigned short* xr = iouxW + (size_t)n * 4 * HDIM + j8;
    us8 xi = *(const us8*)xr;
    us8 xo = *(const us8*)(xr + HDIM);
    us8 xu = *(const us8*)(xr + 2 * HDIM);
    float cv[8], hv[8];
#pragma unroll
    for (int j = 0; j < 8; ++j) {
        cv[j] = sigf(bf2f(xi[j])) * ftanh(bf2f(xu[j]));
        hv[j] = sigf(bf2f(xo[j])) * ftanh(cv[j]);
    }
    float4 c0v = make_float4(cv[0], cv[1], cv[2], cv[3]);
    float4 c1v = make_float4(cv[4], cv[5], cv[6], cv[7]);
    *(float4*)(c_new + (size_t)n * HDIM + j8)     = c0v;
    *(float4*)(c_new + (size_t)n * HDIM + j8 + 4) = c1v;
    us8 hb;
#pragma unroll
    for (int j = 0; j < 8; ++j) hb[j] = f2bf(hv[j]);
    *(us8*)(hb_new + (size_t)n * HDIM + j8) = hb;
}

extern "C" void kernel_launch(void* const* d_in, const int* in_sizes, int n_in,
                              void* d_out, int out_size, void* d_ws, size_t ws_size,
                              hipStream_t stream)
{
    const int*   vocab_ix   = (const int*)d_in[0];     // [L,N]
    const int*   child_idx  = (const int*)d_in[1];     // [L,N,K]
    const float* token_mask = (const float*)d_in[2];   // [L,N]
    const float* child_mask = (const float*)d_in[3];   // [L,N,K]
    const float* embed      = (const float*)d_in[4];   // [V,E] f32
    const float* W_iou      = (const float*)d_in[5];   // [E,3H]
    const float* U_iou      = (const float*)d_in[6];   // [H,3H]
    const float* b_iou      = (const float*)d_in[7];   // [3H]
    const float* W_f        = (const float*)d_in[8];   // [E,H]
    const float* U_f        = (const float*)d_in[9];   // [H,H]
    const float* b_f        = (const float*)d_in[10];  // [H]
    float* out = (float*)d_out;                        // [N,H] level-0 h

    // ---- workspace layout (~217 MB; ws is 256 MiB) ----
    float* ws = (float*)d_ws;
    float* c0 = ws;                                    // [N,H] f32
    float* c1 = c0 + (size_t)NN * HDIM;                // [N,H] f32
    unsigned short* usb   = (unsigned short*)(c1 + (size_t)NN * HDIM);
    unsigned short* hb0   = usb;                                // [N,H] bf16
    unsigned short* hb1   = hb0 + (size_t)NN * HDIM;            // [N,H] bf16
    unsigned short* iouxW = hb1 + (size_t)NN * HDIM;            // [3N,4H] bf16 (3-level batch)
    unsigned short* Z     = iouxW + (size_t)3 * NN * 4 * HDIM;  // [N,4H] bf16
    unsigned short* AbatA = Z + (size_t)NN * 4 * HDIM;          // [3N,EPAD] bf16 (levels 3..5)
    unsigned short* AbatB = AbatA + (size_t)3 * NN * EPAD;      // [3N,EPAD] bf16 (levels 0..2)
    unsigned short* WtALL = AbatB + (size_t)3 * NN * EPAD;      // [4H,EPAD] bf16
    unsigned short* UtALL = WtALL + (size_t)4 * HDIM * EPAD;    // [4H,H] bf16

    dim3 blk(256);

    // ---- converts (every launch; ws is re-poisoned); 2 launches ----
    gconv2_k<<<dim3(6 * NN * (EPAD / 8) / 256), blk, 0, stream>>>(
        embed, vocab_ix, token_mask, AbatA);
    wconvall_k<<<dim3((WCS0 + WCS1 + WCS2 + WCS3) / 256), blk, 0, stream>>>(
        W_iou, W_f, U_iou, U_f, WtALL, UtALL);

    unsigned short* bbuf[2] = { hb0, hb1 };
    float*          cbuf[2] = { c0,  c1  };

    const int ew_blocks = NN * HDIM / 8 / 256;   // 2048

    // Batch A: levels 3..5 (rows l-3), before the recurrence.
    // grid (4 n-groups, 192 m-tiles), NCHUNK=4 -> 768 blocks = 3/CU exactly
    // (full co-residency at the 48KB LDS cap, single dispatch round)
    mgemm_k<1, 4><<<dim3(4, 3 * NN / BM), blk, 0, stream>>>(
        AbatA, WtALL, b_iou, b_f, iouxW, 4 * HDIM, EPAD);

    for (int l = LVLS - 1; l >= 0; --l) {
        const int p = (LVLS - 1 - l);            // 0..5
        unsigned short* hb_new  = bbuf[p & 1];
        float*          c_new   = cbuf[p & 1];
        unsigned short* hb_prev = bbuf[(p & 1) ^ 1];
        float*          c_prev  = cbuf[(p & 1) ^ 1];
        const int*   cix = child_idx  + (size_t)l * NN * KCH;
        const float* cm  = child_mask + (size_t)l * NN * KCH;
        const unsigned short* ix_l =
            iouxW + (size_t)((l >= 3) ? (l - 3) : l) * NN * 4 * HDIM;

        if (l == LVLS - 1) {
            gateleaf_k<<<dim3(ew_blocks), blk, 0, stream>>>(ix_l, c_new, hb_new);
        } else {
            // Z = h_prev @ [U_iou | U_f]   [8192 x 2048 x 512]
            // grid (16 n-tiles, 64 m-tiles) NCHUNK=1 (r7-measured best for Z)
            mgemm_k<0, 1><<<dim3(16, NN / BM), blk, 0, stream>>>(
                hb_prev, UtALL, nullptr, nullptr, Z, 4 * HDIM, HDIM);

            if (l == 0) {
                gatefc_k<true><<<dim3(ew_blocks), blk, 0, stream>>>(
                    ix_l, Z, cix, cm, c_prev, nullptr, nullptr, out);
            } else {
                gatefc_k<false><<<dim3(ew_blocks), blk, 0, stream>>>(
                    ix_l, Z, cix, cm, c_prev, c_new, hb_new, nullptr);
            }
        }

        // After level 3 is consumed, overwrite iouxW with batch B (levels 0..2).
        if (l == 3) {
            mgemm_k<1, 4><<<dim3(4, 3 * NN / BM), blk, 0, stream>>>(
                AbatB, WtALL, b_iou, b_f, iouxW, 4 * HDIM, EPAD);
        }
    }
}

// Round 14
// 551.778 us; speedup vs baseline: 1.0019x; 1.0019x over previous
//
#include <hip/hip_runtime.h>
#include <cmath>

// Problem constants: V=50000, E=300, H=512, L=6, N=8192, K=4
#define VSZ  50000
#define EDIM 300
#define EPAD 320      // E padded to multiple of 32
#define HDIM 512
#define LVLS 6
#define NN   8192
#define KCH  4

// MFMA GEMM tile: 128x128 block, BK=32, 4 waves of 64x64 (4x4 grid of 16x16x32 MFMA)
#define BM 128
#define BN 128
#define BK 32

typedef __attribute__((ext_vector_type(8))) short bf16x8;
typedef __attribute__((ext_vector_type(8))) unsigned short us8;
typedef __attribute__((ext_vector_type(4))) float f32x4;

__device__ __forceinline__ float sigf(float x) { return 1.0f / (1.0f + expf(-x)); }

// fast tanh: 2*sigmoid(2x)-1 — one v_exp + rcp + fma, saturates correctly.
// abs err <= ~1e-6, far below the bf16 rounding already in the pipeline.
// (r13 measured: ~7us saved across the gate kernels vs ocml tanhf.)
__device__ __forceinline__ float ftanh(float x) {
    return 2.0f * sigf(2.0f * x) - 1.0f;
}

__device__ __forceinline__ unsigned short f2bf(float f) {
    unsigned u = __float_as_uint(f);
    u += 0x7FFF + ((u >> 16) & 1);           // RNE
    return (unsigned short)(u >> 16);
}
__device__ __forceinline__ float bf2f(unsigned short h) {
    return __uint_as_float(((unsigned)h) << 16);
}

// HW packed f32->bf16 (RNE), 2 values per instruction
__device__ __forceinline__ unsigned cvt_pk_bf16(float lo, float hi) {
    unsigned r;
    asm("v_cvt_pk_bf16_f32 %0, %1, %2" : "=v"(r) : "v"(lo), "v"(hi));
    return r;
}

// ---- merged gather+convert for BOTH batches (6N rows):
// rows 0..3N-1  (batch A, levels 3..5): vix row = 3N + r
// rows 3N..6N-1 (batch B, levels 0..2): vix row = r - 3N
// out[r][e] = bf16(embed[vix][e] * tmask[vix_row]); e>=EDIM -> 0.
// AbatB is contiguous after AbatA, so a single out base covers both.
__global__ __launch_bounds__(256) void gconv2_k(
    const float* __restrict__ embed, const int* __restrict__ vix,
    const float* __restrict__ tmask, unsigned short* __restrict__ out)
{
    int t  = blockIdx.x * 256 + threadIdx.x;     // 6*NN*40 total
    int r  = t / (EPAD / 8);
    int j8 = (t - r * (EPAD / 8)) * 8;
    int rr = (r < 3 * NN) ? (3 * NN + r) : (r - 3 * NN);
    float m = tmask[rr];
    int   v = vix[rr];
    const float* src = embed + (size_t)v * EDIM + j8;
    us8 o;
    if (j8 + 8 <= EDIM) {
        float4 a = *(const float4*)(src);
        float4 b = *(const float4*)(src + 4);
        const float xs[8] = {a.x, a.y, a.z, a.w, b.x, b.y, b.z, b.w};
#pragma unroll
        for (int j = 0; j < 8; ++j) o[j] = f2bf(xs[j] * m);
    } else {
#pragma unroll
        for (int j = 0; j < 8; ++j) {
            float x = (j8 + j < EDIM) ? src[j] * m : 0.0f;
            o[j] = f2bf(x);
        }
    }
    *(us8*)(out + (size_t)r * EPAD + j8) = o;
}

// ---- merged transpose+convert for all 4 weights (one launch):
// R0: WtALL[0..3H*EPAD)   <- W_iou^T  (k<EDIM real, pad to EPAD)
// R1: WtALL[3H*EPAD..)    <- W_f^T
// R2: UtALL[0..3H*H)      <- U_iou^T  (no pad, Ksp=H)
// R3: UtALL[3H*H..)       <- U_f^T
#define WCS0 (3 * HDIM * EPAD)
#define WCS1 (HDIM * EPAD)
#define WCS2 (3 * HDIM * HDIM)
#define WCS3 (HDIM * HDIM)
__global__ __launch_bounds__(256) void wconvall_k(
    const float* __restrict__ W_iou, const float* __restrict__ W_f,
    const float* __restrict__ U_iou, const float* __restrict__ U_f,
    unsigned short* __restrict__ WtALL, unsigned short* __restrict__ UtALL)
{
    int t = blockIdx.x * 256 + threadIdx.x;     // WCS0+WCS1+WCS2+WCS3 total
    if (t < WCS0) {
        int k = t % EPAD, n = t / EPAD;
        WtALL[t] = (k < EDIM) ? f2bf(W_iou[(size_t)k * (3 * HDIM) + n]) : (unsigned short)0;
    } else if (t < WCS0 + WCS1) {
        int u = t - WCS0;
        int k = u % EPAD, n = u / EPAD;
        WtALL[t] = (k < EDIM) ? f2bf(W_f[(size_t)k * HDIM + n]) : (unsigned short)0;
    } else if (t < WCS0 + WCS1 + WCS2) {
        int u = t - WCS0 - WCS1;
        int k = u % HDIM, n = u / HDIM;
        UtALL[u] = f2bf(U_iou[(size_t)k * (3 * HDIM) + n]);
    } else {
        int u = t - WCS0 - WCS1 - WCS2;
        int k = u % HDIM, n = u / HDIM;
        UtALL[WCS2 + u] = f2bf(U_f[(size_t)k * HDIM + n]);
    }
}

#define GLL(src, dst)                                                        \
    __builtin_amdgcn_global_load_lds(                                        \
        (const __attribute__((address_space(1))) unsigned int*)(src), (dst), 16, 0, 0)

// Dense bf16 GEMM C[M,N] = A[M,Ks] @ Bt[N,Ks]^T
// EPI: 0 = C = bf16(acc); 1 = C = bf16(acc + (col<1536 ? b_iou[col] : b_f[col-1536]))
// Each block processes NCHUNK consecutive N-tiles.
//   Measured (r6-r13): embed GEMM NCHUNK sweep 1/2/4 = 62.4/57.8/62.8 us
//   (FETCH 23/22/30.7 MB) — clean optimum at NCHUNK=2, grid (8,192).
//   Z-GEMM best at (16,64)/NCHUNK=1. Direct-store epilogue REGRESSED (r8);
//   distance-3/64KB REGRESSED (r10). Body: 3-stage, dist 2, 48KB (r9/r11).
// XCD-aware swizzle: linear block id P -> XCD g=P%8 owns a contiguous band of
// M-tiles with ALL n-groups, so A-band + B panels are L2-resident per XCD.
// Requires gridDim.y % 8 == 0.
// K-loop (T3+T4, 3-stage): triple-buffer rotation, prefetch distance 2,
// ONE barrier per K-step:
//   per interval i: STAGE(k[i+2] -> buf[(i+2)%3]); COMPUTE(buf[i%3]);
//                   s_waitcnt vmcnt(4); s_barrier.
// Safety: waves all sit between barrier i-1 and i, so the staged buffer
// (== buf[i-1]) was finished by every wave before barrier i-1. The counted
// wait covers loads issued a FULL compute interval ago (cheap), and the
// prefetch stays in flight across the barrier (never vmcnt(0) mid-loop).
// LDS: 3 x 16 KB buffers = 48 KB (3 blocks/CU cap); XOR-swizzled 16B
// granules via global_load_lds (wave-uniform dest).
// Epilogue: LDS-transposed (32x128 f32 stripes in buffer 0, XOR-granule
// swizzle), v_cvt_pk_bf16_f32 conversion, coalesced dwordx4 stores.
template <int EPI, int NCHUNK>
__global__ __launch_bounds__(256) void mgemm_k(
    const unsigned short* __restrict__ Ab,
    const unsigned short* __restrict__ Bt,
    const float* __restrict__ b_iou, const float* __restrict__ b_f,
    unsigned short* __restrict__ C, int ldc, int Ks)
{
    // 3 buffers of (A 4096 shorts | B 4096 shorts) = 48 KB total
    __shared__ __align__(16) unsigned short smem[6 * BM * BK];

    const int tid  = threadIdx.x;
    const int wave = tid >> 6;
    const int lane = tid & 63;
    const int quad = lane >> 4;
    const int mcol = lane & 15;
    const int wm   = (wave >> 1) * 64;
    const int wn   = (wave & 1) * 64;
    const int band = wave >> 1;

    // ---- XCD swizzle (bijective; gridDim.y % 8 == 0) ----
    const int GX   = gridDim.x;                 // n-groups
    const int P    = blockIdx.x + GX * blockIdx.y;
    const int g    = P & 7;
    const int s    = P >> 3;
    const int mper = gridDim.y >> 3;
    const int sdiv = s / GX;
    const int my_mt = g * mper + sdiv;          // m-tile
    const int my_ng = s - sdiv * GX;            // n-group
    const int tile_m = my_mt * BM;

    // staging: thread handles chunks c0=tid, c1=tid+256 (identity LDS placement)
    const int r0  = tid >> 2;
    const int kg0 = (tid & 3) ^ ((r0 >> 1) & 3);
    const int cc1 = tid + 256;
    const int r1  = cc1 >> 2;
    const int kg1 = (cc1 & 3) ^ ((r1 >> 1) & 3);

    const unsigned short* asrc0 = Ab + (size_t)(tile_m + r0) * Ks + kg0 * 8;
    const unsigned short* asrc1 = Ab + (size_t)(tile_m + r1) * Ks + kg1 * 8;

    typedef __attribute__((address_space(3))) unsigned int lds_u32;

    // epilogue views/indices (eb = buffer-0 region, 16 KB)
    float* eb = reinterpret_cast<float*>(smem);          // 32x128 f32
    const int erl = tid >> 3;                            // 0..31 (stripe row)
    const int ecg = tid & 7;                             // 0..7  (16-col group)

// stage K-slice kk into buffer at short-offset bo (A at bo, B at bo+4096)
#define STAGE3(kk, bo)                                                       \
    {                                                                        \
        GLL(asrc0 + (kk), (lds_u32*)(smem + (bo) + wave * 512));             \
        GLL(asrc1 + (kk), (lds_u32*)(smem + (bo) + 2048 + wave * 512));      \
        GLL(bsrc0 + (kk), (lds_u32*)(smem + (bo) + 4096 + wave * 512));      \
        GLL(bsrc1 + (kk), (lds_u32*)(smem + (bo) + 6144 + wave * 512));      \
    }
#define WAITV4  asm volatile("s_waitcnt vmcnt(4)" ::: "memory")
#define WAITV0  asm volatile("s_waitcnt vmcnt(0)" ::: "memory")
#define BAR     __builtin_amdgcn_s_barrier()

#define COMPUTE(bo)                                                         \
    {                                                                       \
        const unsigned short* AS = smem + (bo);                             \
        const unsigned short* BS = smem + (bo) + 4096;                      \
        bf16x8 afr[4], bfr[4];                                              \
        _Pragma("unroll")                                                   \
        for (int mt = 0; mt < 4; ++mt) {                                    \
            int rw = wm + mt * 16 + mcol;                                   \
            int p  = rw * 4 + (quad ^ ((rw >> 1) & 3));                     \
            afr[mt] = *(const bf16x8*)(AS + p * 8);                         \
        }                                                                   \
        _Pragma("unroll")                                                   \
        for (int nt = 0; nt < 4; ++nt) {                                    \
            int rw = wn + nt * 16 + mcol;                                   \
            int p  = rw * 4 + (quad ^ ((rw >> 1) & 3));                     \
            bfr[nt] = *(const bf16x8*)(BS + p * 8);                         \
        }                                                                   \
        _Pragma("unroll")                                                   \
        for (int mt = 0; mt < 4; ++mt)                                      \
            _Pragma("unroll")                                               \
            for (int nt = 0; nt < 4; ++nt)                                  \
                acc[mt][nt] = __builtin_amdgcn_mfma_f32_16x16x32_bf16(      \
                    afr[mt], bfr[nt], acc[mt][nt], 0, 0, 0);                \
    }

    for (int nc = 0; nc < NCHUNK; ++nc) {
        const int tile_n = (my_ng * NCHUNK + nc) * BN;
        const unsigned short* bsrc0 = Bt + (size_t)(tile_n + r0) * Ks + kg0 * 8;
        const unsigned short* bsrc1 = Bt + (size_t)(tile_n + r1) * Ks + kg1 * 8;

        f32x4 acc[4][4] = {};
        const int nsteps = Ks / BK;              // 10 or 16

        // rotating buffer offsets (shorts): 16 KB apart
        int bo0 = 0, bo1 = 8192, bo2 = 16384;

        // prologue: fill buf0, buf1; wait buf0 only
        STAGE3(0, bo0);
        STAGE3(BK, bo1);
        WAITV4;
        BAR;

        for (int st = 0; st < nsteps; ++st) {
            const bool pf = (st + 2 < nsteps);
            if (pf) STAGE3((st + 2) * BK, bo2);
            COMPUTE(bo0);
            if (pf) { WAITV4; } else { WAITV0; }
            BAR;
            int t0 = bo0; bo0 = bo1; bo1 = bo2; bo2 = t0;
        }

        // ---- epilogue: 4 stripes of 32 rows x 128 cols f32 through LDS ----
        // writer: value acc[mt][nt][rr] is logical (r = band*16+quad*4+rr,
        //         c = wn+nt*16+mcol); phys granule = (c>>2) ^ (r&7).
        // reader: thread handles row erl, cols ecg*16..+15 -> 2 dwordx4 stores.
#pragma unroll
        for (int mt = 0; mt < 4; ++mt) {
            const int rbase = band * 16 + quad * 4;
#pragma unroll
            for (int nt = 0; nt < 4; ++nt) {
                const int cb = wn + nt * 16 + mcol;
                const int gq = cb >> 2;
                const int cl = cb & 3;
#pragma unroll
                for (int rr = 0; rr < 4; ++rr) {
                    const int r = rbase + rr;
                    eb[r * 128 + ((gq ^ (r & 7)) << 2) + cl] = acc[mt][nt][rr];
                }
            }
            __syncthreads();

            const int grow = tile_m + (erl >> 4) * 64 + mt * 16 + (erl & 15);
            const int gcol = tile_n + ecg * 16;
            float v[16];
#pragma unroll
            for (int sxt = 0; sxt < 4; ++sxt) {
                const int pg = (ecg * 4 + sxt) ^ (erl & 7);
                f32x4 q = *(const f32x4*)&eb[erl * 128 + pg * 4];
                v[sxt * 4 + 0] = q[0]; v[sxt * 4 + 1] = q[1];
                v[sxt * 4 + 2] = q[2]; v[sxt * 4 + 3] = q[3];
            }
            if (EPI == 1) {
                const float* bp = (gcol < 3 * HDIM) ? (b_iou + gcol)
                                                    : (b_f + gcol - 3 * HDIM);
                float4 b0 = *(const float4*)(bp);
                float4 b1 = *(const float4*)(bp + 4);
                float4 b2 = *(const float4*)(bp + 8);
                float4 b3 = *(const float4*)(bp + 12);
                const float bb[16] = {b0.x, b0.y, b0.z, b0.w, b1.x, b1.y, b1.z, b1.w,
                                      b2.x, b2.y, b2.z, b2.w, b3.x, b3.y, b3.z, b3.w};
#pragma unroll
                for (int j = 0; j < 16; ++j) v[j] += bb[j];
            }
            unsigned pw[8];
#pragma unroll
            for (int j = 0; j < 8; ++j) pw[j] = cvt_pk_bf16(v[2 * j], v[2 * j + 1]);
            unsigned short* cp = C + (size_t)grow * ldc + gcol;
            *(uint4*)(cp)     = make_uint4(pw[0], pw[1], pw[2], pw[3]);
            *(uint4*)(cp + 8) = make_uint4(pw[4], pw[5], pw[6], pw[7]);
            __syncthreads();
        }
    }
#undef STAGE3
#undef WAITV4
#undef WAITV0
#undef BAR
#undef COMPUTE
}

// fused child-sum + fc + gates (non-leaf).
// iouxW row: bf16 [i|o|u|xwf+bf] (2048). Z row: bf16 [h@U_iou (1536) | h@U_f (512)].
//   ia = i + sum_k m_k * Zi[c_k] ; (same o,u) ; fc = sum_k sigf(xw + m_k*Zf[c_k]) * m_k * c_prev[c_k]
//   c = sigf(ia)*tanh(ua) + fc ; h = sigf(oa)*tanh(c)
// MASK-SKIP (r12, measured -21us): n = t>>6 is WAVE-UNIFORM, so `if (m!=0)`
// is a uniform branch — skipping masked children (~25%) eliminates their
// gathers + VALU exactly, no divergence.
// ftanh (r13, measured ~-7us total): tanhf -> 2*sigmoid(2x)-1.
// LAST: write h f32 to h_out only; else write c_new f32 + hb_new bf16.
template <bool LAST>
__global__ __launch_bounds__(256) void gatefc_k(
    const unsigned short* __restrict__ iouxW, const unsigned short* __restrict__ Z,
    const int* __restrict__ cidx, const float* __restrict__ cmask,
    const float* __restrict__ c_prev,
    float* __restrict__ c_new, unsigned short* __restrict__ hb_new,
    float* __restrict__ h_out)
{
    int t  = blockIdx.x * 256 + threadIdx.x;   // NN*HDIM/8 threads
    int n  = t >> 6;
    int j8 = (t & 63) << 3;
    const unsigned short* xr = iouxW + (size_t)n * 4 * HDIM + j8;
    us8 xi = *(const us8*)xr;
    us8 xo = *(const us8*)(xr + HDIM);
    us8 xu = *(const us8*)(xr + 2 * HDIM);
    us8 xf = *(const us8*)(xr + 3 * HDIM);
    float ia[8], oa[8], ua[8], xw[8], fc[8];
#pragma unroll
    for (int j = 0; j < 8; ++j) {
        ia[j] = bf2f(xi[j]); oa[j] = bf2f(xo[j]);
        ua[j] = bf2f(xu[j]); xw[j] = bf2f(xf[j]);
        fc[j] = 0.0f;
    }
    int4   ci = *(const int4*)&cidx[n * KCH];
    float4 cm = *(const float4*)&cmask[n * KCH];
    const int   cia[4] = {ci.x, ci.y, ci.z, ci.w};
    const float cma[4] = {cm.x, cm.y, cm.z, cm.w};
#pragma unroll
    for (int k = 0; k < KCH; ++k) {
        const float m = cma[k];
        if (m != 0.0f) {                       // wave-uniform branch
            const unsigned short* zr = Z + (size_t)cia[k] * 4 * HDIM + j8;
            us8 zi = *(const us8*)zr;
            us8 zo = *(const us8*)(zr + HDIM);
            us8 zu = *(const us8*)(zr + 2 * HDIM);
            us8 zf = *(const us8*)(zr + 3 * HDIM);
            const float* cpr = c_prev + (size_t)cia[k] * HDIM + j8;
            float4 ca = *(const float4*)cpr;
            float4 cb = *(const float4*)(cpr + 4);
            const float cp[8] = {ca.x, ca.y, ca.z, ca.w, cb.x, cb.y, cb.z, cb.w};
#pragma unroll
            for (int j = 0; j < 8; ++j) {
                ia[j] += m * bf2f(zi[j]);
                oa[j] += m * bf2f(zo[j]);
                ua[j] += m * bf2f(zu[j]);
                fc[j] += sigf(xw[j] + m * bf2f(zf[j])) * m * cp[j];
            }
        }
    }
    float cv[8], hv[8];
#pragma unroll
    for (int j = 0; j < 8; ++j) {
        cv[j] = sigf(ia[j]) * ftanh(ua[j]) + fc[j];
        hv[j] = sigf(oa[j]) * ftanh(cv[j]);
    }
    if (LAST) {
        float4 h0 = make_float4(hv[0], hv[1], hv[2], hv[3]);
        float4 h1 = make_float4(hv[4], hv[5], hv[6], hv[7]);
        *(float4*)(h_out + (size_t)n * HDIM + j8)     = h0;
        *(float4*)(h_out + (size_t)n * HDIM + j8 + 4) = h1;
    } else {
        float4 c0v = make_float4(cv[0], cv[1], cv[2], cv[3]);
        float4 c1v = make_float4(cv[4], cv[5], cv[6], cv[7]);
        *(float4*)(c_new + (size_t)n * HDIM + j8)     = c0v;
        *(float4*)(c_new + (size_t)n * HDIM + j8 + 4) = c1v;
        us8 hb;
#pragma unroll
        for (int j = 0; j < 8; ++j) hb[j] = f2bf(hv[j]);
        *(us8*)(hb_new + (size_t)n * HDIM + j8) = hb;
    }
}

// leaf: fc = 0, no children
__global__ __launch_bounds__(256) void gateleaf_k(
    const unsigned short* __restrict__ iouxW,
    float* __restrict__ c_new, unsigned short* __restrict__ hb_new)
{
    int t  = blockIdx.x * 256 + threadIdx.x;
    int n  = t >> 6;
    int j8 = (t & 63) << 3;
    const unsigned short* xr = iouxW + (size_t)n * 4 * HDIM + j8;
    us8 xi = *(const us8*)xr;
    us8 xo = *(const us8*)(xr + HDIM);
    us8 xu = *(const us8*)(xr + 2 * HDIM);
    float cv[8], hv[8];
#pragma unroll
    for (int j = 0; j < 8; ++j) {
        cv[j] = sigf(bf2f(xi[j])) * ftanh(bf2f(xu[j]));
        hv[j] = sigf(bf2f(xo[j])) * ftanh(cv[j]);
    }
    float4 c0v = make_float4(cv[0], cv[1], cv[2], cv[3]);
    float4 c1v = make_float4(cv[4], cv[5], cv[6], cv[7]);
    *(float4*)(c_new + (size_t)n * HDIM + j8)     = c0v;
    *(float4*)(c_new + (size_t)n * HDIM + j8 + 4) = c1v;
    us8 hb;
#pragma unroll
    for (int j = 0; j < 8; ++j) hb[j] = f2bf(hv[j]);
    *(us8*)(hb_new + (size_t)n * HDIM + j8) = hb;
}

extern "C" void kernel_launch(void* const* d_in, const int* in_sizes, int n_in,
                              void* d_out, int out_size, void* d_ws, size_t ws_size,
                              hipStream_t stream)
{
    const int*   vocab_ix   = (const int*)d_in[0];     // [L,N]
    const int*   child_idx  = (const int*)d_in[1];     // [L,N,K]
    const float* token_mask = (const float*)d_in[2];   // [L,N]
    const float* child_mask = (const float*)d_in[3];   // [L,N,K]
    const float* embed      = (const float*)d_in[4];   // [V,E] f32
    const float* W_iou      = (const float*)d_in[5];   // [E,3H]
    const float* U_iou      = (const float*)d_in[6];   // [H,3H]
    const float* b_iou      = (const float*)d_in[7];   // [3H]
    const float* W_f        = (const float*)d_in[8];   // [E,H]
    const float* U_f        = (const float*)d_in[9];   // [H,H]
    const float* b_f        = (const float*)d_in[10];  // [H]
    float* out = (float*)d_out;                        // [N,H] level-0 h

    // ---- workspace layout (~217 MB; ws is 256 MiB) ----
    float* ws = (float*)d_ws;
    float* c0 = ws;                                    // [N,H] f32
    float* c1 = c0 + (size_t)NN * HDIM;                // [N,H] f32
    unsigned short* usb   = (unsigned short*)(c1 + (size_t)NN * HDIM);
    unsigned short* hb0   = usb;                                // [N,H] bf16
    unsigned short* hb1   = hb0 + (size_t)NN * HDIM;            // [N,H] bf16
    unsigned short* iouxW = hb1 + (size_t)NN * HDIM;            // [3N,4H] bf16 (3-level batch)
    unsigned short* Z     = iouxW + (size_t)3 * NN * 4 * HDIM;  // [N,4H] bf16
    unsigned short* AbatA = Z + (size_t)NN * 4 * HDIM;          // [3N,EPAD] bf16 (levels 3..5)
    unsigned short* AbatB = AbatA + (size_t)3 * NN * EPAD;      // [3N,EPAD] bf16 (levels 0..2)
    unsigned short* WtALL = AbatB + (size_t)3 * NN * EPAD;      // [4H,EPAD] bf16
    unsigned short* UtALL = WtALL + (size_t)4 * HDIM * EPAD;    // [4H,H] bf16

    dim3 blk(256);

    // ---- converts (every launch; ws is re-poisoned); 2 launches ----
    gconv2_k<<<dim3(6 * NN * (EPAD / 8) / 256), blk, 0, stream>>>(
        embed, vocab_ix, token_mask, AbatA);
    wconvall_k<<<dim3((WCS0 + WCS1 + WCS2 + WCS3) / 256), blk, 0, stream>>>(
        W_iou, W_f, U_iou, U_f, WtALL, UtALL);

    unsigned short* bbuf[2] = { hb0, hb1 };
    float*          cbuf[2] = { c0,  c1  };

    const int ew_blocks = NN * HDIM / 8 / 256;   // 2048

    // Batch A: levels 3..5 (rows l-3), before the recurrence.
    // grid (8 n-groups, 192 m-tiles), NCHUNK=2 (measured optimum r6/r11)
    mgemm_k<1, 2><<<dim3(8, 3 * NN / BM), blk, 0, stream>>>(
        AbatA, WtALL, b_iou, b_f, iouxW, 4 * HDIM, EPAD);

    for (int l = LVLS - 1; l >= 0; --l) {
        const int p = (LVLS - 1 - l);            // 0..5
        unsigned short* hb_new  = bbuf[p & 1];
        float*          c_new   = cbuf[p & 1];
        unsigned short* hb_prev = bbuf[(p & 1) ^ 1];
        float*          c_prev  = cbuf[(p & 1) ^ 1];
        const int*   cix = child_idx  + (size_t)l * NN * KCH;
        const float* cm  = child_mask + (size_t)l * NN * KCH;
        const unsigned short* ix_l =
            iouxW + (size_t)((l >= 3) ? (l - 3) : l) * NN * 4 * HDIM;

        if (l == LVLS - 1) {
            gateleaf_k<<<dim3(ew_blocks), blk, 0, stream>>>(ix_l, c_new, hb_new);
        } else {
            // Z = h_prev @ [U_iou | U_f]   [8192 x 2048 x 512]
            // grid (16 n-tiles, 64 m-tiles) NCHUNK=1 (r7-measured best for Z)
            mgemm_k<0, 1><<<dim3(16, NN / BM), blk, 0, stream>>>(
                hb_prev, UtALL, nullptr, nullptr, Z, 4 * HDIM, HDIM);

            if (l == 0) {
                gatefc_k<true><<<dim3(ew_blocks), blk, 0, stream>>>(
                    ix_l, Z, cix, cm, c_prev, nullptr, nullptr, out);
            } else {
                gatefc_k<false><<<dim3(ew_blocks), blk, 0, stream>>>(
                    ix_l, Z, cix, cm, c_prev, c_new, hb_new, nullptr);
            }
        }

        // After level 3 is consumed, overwrite iouxW with batch B (levels 0..2).
        if (l == 3) {
            mgemm_k<1, 2><<<dim3(8, 3 * NN / BM), blk, 0, stream>>>(
                AbatB, WtALL, b_iou, b_f, iouxW, 4 * HDIM, EPAD);
        }
    }
}

// Round 18
// 544.101 us; speedup vs baseline: 1.0160x; 1.0141x over previous
//
#include <hip/hip_runtime.h>
#include <cmath>

// Problem constants: V=50000, E=300, H=512, L=6, N=8192, K=4
#define VSZ  50000
#define EDIM 300
#define EPAD 320      // E padded to multiple of 32
#define HDIM 512
#define LVLS 6
#define NN   8192
#define KCH  4

// MFMA GEMM tile: 128x128 block, BK=32, 4 waves of 64x64 (4x4 grid of 16x16x32 MFMA)
#define BM 128
#define BN 128
#define BK 32

typedef __attribute__((ext_vector_type(8))) short bf16x8;
typedef __attribute__((ext_vector_type(8))) unsigned short us8;
typedef __attribute__((ext_vector_type(4))) float f32x4;

__device__ __forceinline__ float sigf(float x) { return 1.0f / (1.0f + expf(-x)); }

// fast tanh: 2*sigmoid(2x)-1 — one v_exp + rcp + fma, saturates correctly.
__device__ __forceinline__ float ftanh(float x) {
    return 2.0f * sigf(2.0f * x) - 1.0f;
}

__device__ __forceinline__ unsigned short f2bf(float f) {
    unsigned u = __float_as_uint(f);
    u += 0x7FFF + ((u >> 16) & 1);           // RNE
    return (unsigned short)(u >> 16);
}
__device__ __forceinline__ float bf2f(unsigned short h) {
    return __uint_as_float(((unsigned)h) << 16);
}

// HW packed f32->bf16 (RNE), 2 values per instruction
__device__ __forceinline__ unsigned cvt_pk_bf16(float lo, float hi) {
    unsigned r;
    asm("v_cvt_pk_bf16_f32 %0, %1, %2" : "=v"(r) : "v"(lo), "v"(hi));
    return r;
}

// ---- merged gather+convert for BOTH batches (6N rows):
// rows 0..3N-1  (batch A, levels 3..5): vix row = 3N + r
// rows 3N..6N-1 (batch B, levels 0..2): vix row = r - 3N
__global__ __launch_bounds__(256) void gconv2_k(
    const float* __restrict__ embed, const int* __restrict__ vix,
    const float* __restrict__ tmask, unsigned short* __restrict__ out)
{
    int t  = blockIdx.x * 256 + threadIdx.x;     // 6*NN*40 total
    int r  = t / (EPAD / 8);
    int j8 = (t - r * (EPAD / 8)) * 8;
    int rr = (r < 3 * NN) ? (3 * NN + r) : (r - 3 * NN);
    float m = tmask[rr];
    int   v = vix[rr];
    const float* src = embed + (size_t)v * EDIM + j8;
    us8 o;
    if (j8 + 8 <= EDIM) {
        float4 a = *(const float4*)(src);
        float4 b = *(const float4*)(src + 4);
        const float xs[8] = {a.x, a.y, a.z, a.w, b.x, b.y, b.z, b.w};
#pragma unroll
        for (int j = 0; j < 8; ++j) o[j] = f2bf(xs[j] * m);
    } else {
#pragma unroll
        for (int j = 0; j < 8; ++j) {
            float x = (j8 + j < EDIM) ? src[j] * m : 0.0f;
            o[j] = f2bf(x);
        }
    }
    *(us8*)(out + (size_t)r * EPAD + j8) = o;
}

// ---- merged transpose+convert for all 4 weights (one launch) ----
#define WCS0 (3 * HDIM * EPAD)
#define WCS1 (HDIM * EPAD)
#define WCS2 (3 * HDIM * HDIM)
#define WCS3 (HDIM * HDIM)
__global__ __launch_bounds__(256) void wconvall_k(
    const float* __restrict__ W_iou, const float* __restrict__ W_f,
    const float* __restrict__ U_iou, const float* __restrict__ U_f,
    unsigned short* __restrict__ WtALL, unsigned short* __restrict__ UtALL)
{
    int t = blockIdx.x * 256 + threadIdx.x;     // WCS0+WCS1+WCS2+WCS3 total
    if (t < WCS0) {
        int k = t % EPAD, n = t / EPAD;
        WtALL[t] = (k < EDIM) ? f2bf(W_iou[(size_t)k * (3 * HDIM) + n]) : (unsigned short)0;
    } else if (t < WCS0 + WCS1) {
        int u = t - WCS0;
        int k = u % EPAD, n = u / EPAD;
        WtALL[t] = (k < EDIM) ? f2bf(W_f[(size_t)k * HDIM + n]) : (unsigned short)0;
    } else if (t < WCS0 + WCS1 + WCS2) {
        int u = t - WCS0 - WCS1;
        int k = u % HDIM, n = u / HDIM;
        UtALL[u] = f2bf(U_iou[(size_t)k * (3 * HDIM) + n]);
    } else {
        int u = t - WCS0 - WCS1 - WCS2;
        int k = u % HDIM, n = u / HDIM;
        UtALL[WCS2 + u] = f2bf(U_f[(size_t)k * HDIM + n]);
    }
}

#define GLL(src, dst)                                                        \
    __builtin_amdgcn_global_load_lds(                                        \
        (const __attribute__((address_space(1))) unsigned int*)(src), (dst), 16, 0, 0)

// Dense bf16 GEMM C[M,N] = A[M,Ks] @ Bt[N,Ks]^T
// EPI: 0 = C = bf16(acc); 1 = C = bf16(acc + (col<1536 ? b_iou[col] : b_f[col-1536]))
//   Measured (r6-r15): embed best (8,192)/NCHUNK=2 (sweep 1/2/4 =
//   62.4/57.8/62.8 us); Z best (16,64)/NCHUNK=1. Direct-store epilogue
//   REGRESSED (r8); distance-3/64KB REGRESSED (r10); KS-templated FULL
//   UNROLL BROKE CORRECTNESS (r15: straight-lining let the compiler
//   re-schedule loads across iteration boundaries, defeating the
//   counted-vmcnt pipeline — keep the runtime loop).
//   Body: 3-stage, distance 2, 48KB (r9/r11/r14-verified).
// XCD-aware swizzle: bijective; requires gridDim.y % 8 == 0.
// K-loop (T3+T4, 3-stage): per step: STAGE(k+2 -> bo2); COMPUTE(bo0);
//   s_waitcnt vmcnt(4); s_barrier; rotate. Prefetch never drains mid-loop.
template <int EPI, int NCHUNK>
__global__ __launch_bounds__(256) void mgemm_k(
    const unsigned short* __restrict__ Ab,
    const unsigned short* __restrict__ Bt,
    const float* __restrict__ b_iou, const float* __restrict__ b_f,
    unsigned short* __restrict__ C, int ldc, int Ks)
{
    // 3 buffers of (A 4096 shorts | B 4096 shorts) = 48 KB total
    __shared__ __align__(16) unsigned short smem[6 * BM * BK];

    const int tid  = threadIdx.x;
    const int wave = tid >> 6;
    const int lane = tid & 63;
    const int quad = lane >> 4;
    const int mcol = lane & 15;
    const int wm   = (wave >> 1) * 64;
    const int wn   = (wave & 1) * 64;
    const int band = wave >> 1;

    // ---- XCD swizzle (bijective; gridDim.y % 8 == 0) ----
    const int GX   = gridDim.x;                 // n-groups
    const int P    = blockIdx.x + GX * blockIdx.y;
    const int g    = P & 7;
    const int s    = P >> 3;
    const int mper = gridDim.y >> 3;
    const int sdiv = s / GX;
    const int my_mt = g * mper + sdiv;          // m-tile
    const int my_ng = s - sdiv * GX;            // n-group
    const int tile_m = my_mt * BM;

    // staging: thread handles chunks c0=tid, c1=tid+256 (identity LDS placement)
    const int r0  = tid >> 2;
    const int kg0 = (tid & 3) ^ ((r0 >> 1) & 3);
    const int cc1 = tid + 256;
    const int r1  = cc1 >> 2;
    const int kg1 = (cc1 & 3) ^ ((r1 >> 1) & 3);

    const unsigned short* asrc0 = Ab + (size_t)(tile_m + r0) * Ks + kg0 * 8;
    const unsigned short* asrc1 = Ab + (size_t)(tile_m + r1) * Ks + kg1 * 8;

    typedef __attribute__((address_space(3))) unsigned int lds_u32;

    // epilogue views/indices (eb = buffer-0 region, 16 KB)
    float* eb = reinterpret_cast<float*>(smem);          // 32x128 f32
    const int erl = tid >> 3;                            // 0..31 (stripe row)
    const int ecg = tid & 7;                             // 0..7  (16-col group)

// stage K-slice kk into buffer at short-offset bo (A at bo, B at bo+4096)
#define STAGE3(kk, bo)                                                       \
    {                                                                        \
        GLL(asrc0 + (kk), (lds_u32*)(smem + (bo) + wave * 512));             \
        GLL(asrc1 + (kk), (lds_u32*)(smem + (bo) + 2048 + wave * 512));      \
        GLL(bsrc0 + (kk), (lds_u32*)(smem + (bo) + 4096 + wave * 512));      \
        GLL(bsrc1 + (kk), (lds_u32*)(smem + (bo) + 6144 + wave * 512));      \
    }
#define WAITV4  asm volatile("s_waitcnt vmcnt(4)" ::: "memory")
#define WAITV0  asm volatile("s_waitcnt vmcnt(0)" ::: "memory")
#define BAR     __builtin_amdgcn_s_barrier()

#define COMPUTE(bo)                                                         \
    {                                                                       \
        const unsigned short* AS = smem + (bo);                             \
        const unsigned short* BS = smem + (bo) + 4096;                      \
        bf16x8 afr[4], bfr[4];                                              \
        _Pragma("unroll")                                                   \
        for (int mt = 0; mt < 4; ++mt) {                                    \
            int rw = wm + mt * 16 + mcol;                                   \
            int p  = rw * 4 + (quad ^ ((rw >> 1) & 3));                     \
            afr[mt] = *(const bf16x8*)(AS + p * 8);                         \
        }                                                                   \
        _Pragma("unroll")                                                   \
        for (int nt = 0; nt < 4; ++nt) {                                    \
            int rw = wn + nt * 16 + mcol;                                   \
            int p  = rw * 4 + (quad ^ ((rw >> 1) & 3));                     \
            bfr[nt] = *(const bf16x8*)(BS + p * 8);                         \
        }                                                                   \
        _Pragma("unroll")                                                   \
        for (int mt = 0; mt < 4; ++mt)                                      \
            _Pragma("unroll")                                               \
            for (int nt = 0; nt < 4; ++nt)                                  \
                acc[mt][nt] = __builtin_amdgcn_mfma_f32_16x16x32_bf16(      \
                    afr[mt], bfr[nt], acc[mt][nt], 0, 0, 0);                \
    }

    for (int nc = 0; nc < NCHUNK; ++nc) {
        const int tile_n = (my_ng * NCHUNK + nc) * BN;
        const unsigned short* bsrc0 = Bt + (size_t)(tile_n + r0) * Ks + kg0 * 8;
        const unsigned short* bsrc1 = Bt + (size_t)(tile_n + r1) * Ks + kg1 * 8;

        f32x4 acc[4][4] = {};
        const int nsteps = Ks / BK;              // 10 or 16

        // rotating buffer offsets (shorts): 16 KB apart
        int bo0 = 0, bo1 = 8192, bo2 = 16384;

        // prologue: fill buf0, buf1; wait buf0 only
        STAGE3(0, bo0);
        STAGE3(BK, bo1);
        WAITV4;
        BAR;

        for (int st = 0; st < nsteps; ++st) {
            const bool pf = (st + 2 < nsteps);
            if (pf) STAGE3((st + 2) * BK, bo2);
            COMPUTE(bo0);
            if (pf) { WAITV4; } else { WAITV0; }
            BAR;
            int t0 = bo0; bo0 = bo1; bo1 = bo2; bo2 = t0;
        }

        // ---- epilogue: 4 stripes of 32 rows x 128 cols f32 through LDS ----
        // writer: value acc[mt][nt][rr] is logical (r = band*16+quad*4+rr,
        //         c = wn+nt*16+mcol); phys granule = (c>>2) ^ (r&7).
        // reader: thread handles row erl, cols ecg*16..+15 -> 2 dwordx4 stores.
#pragma unroll
        for (int mt = 0; mt < 4; ++mt) {
            const int rbase = band * 16 + quad * 4;
#pragma unroll
            for (int nt = 0; nt < 4; ++nt) {
                const int cb = wn + nt * 16 + mcol;
                const int gq = cb >> 2;
                const int cl = cb & 3;
#pragma unroll
                for (int rr = 0; rr < 4; ++rr) {
                    const int r = rbase + rr;
                    eb[r * 128 + ((gq ^ (r & 7)) << 2) + cl] = acc[mt][nt][rr];
                }
            }
            __syncthreads();

            const int grow = tile_m + (erl >> 4) * 64 + mt * 16 + (erl & 15);
            const int gcol = tile_n + ecg * 16;
            float v[16];
#pragma unroll
            for (int sxt = 0; sxt < 4; ++sxt) {
                const int pg = (ecg * 4 + sxt) ^ (erl & 7);
                f32x4 q = *(const f32x4*)&eb[erl * 128 + pg * 4];
                v[sxt * 4 + 0] = q[0]; v[sxt * 4 + 1] = q[1];
                v[sxt * 4 + 2] = q[2]; v[sxt * 4 + 3] = q[3];
            }
            if (EPI == 1) {
                const float* bp = (gcol < 3 * HDIM) ? (b_iou + gcol)
                                                    : (b_f + gcol - 3 * HDIM);
                float4 b0 = *(const float4*)(bp);
                float4 b1 = *(const float4*)(bp + 4);
                float4 b2 = *(const float4*)(bp + 8);
                float4 b3 = *(const float4*)(bp + 12);
                const float bb[16] = {b0.x, b0.y, b0.z, b0.w, b1.x, b1.y, b1.z, b1.w,
                                      b2.x, b2.y, b2.z, b2.w, b3.x, b3.y, b3.z, b3.w};
#pragma unroll
                for (int j = 0; j < 16; ++j) v[j] += bb[j];
            }
            unsigned pw[8];
#pragma unroll
            for (int j = 0; j < 8; ++j) pw[j] = cvt_pk_bf16(v[2 * j], v[2 * j + 1]);
            unsigned short* cp = C + (size_t)grow * ldc + gcol;
            *(uint4*)(cp)     = make_uint4(pw[0], pw[1], pw[2], pw[3]);
            *(uint4*)(cp + 8) = make_uint4(pw[4], pw[5], pw[6], pw[7]);
            __syncthreads();
        }
    }
#undef STAGE3
#undef WAITV4
#undef WAITV0
#undef BAR
#undef COMPUTE
}

// fused child-sum + fc + gates (non-leaf).
// iouxW row: bf16 [i|o|u|xwf+bf] (2048). Z row: bf16 [h@U_iou (1536) | h@U_f (512)].
//   ia = i + sum_k m_k * Zi[c_k] ; (same o,u) ; fc = sum_k sigf(xw + m_k*Zf[c_k]) * m_k * c_prev[c_k]
//   c = sigf(ia)*tanh(ua) + fc ; h = sigf(oa)*tanh(c)
// MASK-SKIP (r12, measured -21us): n = t>>6 is WAVE-UNIFORM, so `if (m!=0)`
// is a uniform branch — skipping masked children (~25%) eliminates their
// gathers + VALU exactly, no divergence. (r16/r17's unconditional-gather
// variant never got a clean measurement — two container failures; parked.)
// ftanh (r13): tanhf -> 2*sigmoid(2x)-1.
// LAST: write h f32 to h_out only; else write c_new f32 + hb_new bf16.
template <bool LAST>
__global__ __launch_bounds__(256) void gatefc_k(
    const unsigned short* __restrict__ iouxW, const unsigned short* __restrict__ Z,
    const int* __restrict__ cidx, const float* __restrict__ cmask,
    const float* __restrict__ c_prev,
    float* __restrict__ c_new, unsigned short* __restrict__ hb_new,
    float* __restrict__ h_out)
{
    int t  = blockIdx.x * 256 + threadIdx.x;   // NN*HDIM/8 threads
    int n  = t >> 6;
    int j8 = (t & 63) << 3;
    const unsigned short* xr = iouxW + (size_t)n * 4 * HDIM + j8;
    us8 xi = *(const us8*)xr;
    us8 xo = *(const us8*)(xr + HDIM);
    us8 xu = *(const us8*)(xr + 2 * HDIM);
    us8 xf = *(const us8*)(xr + 3 * HDIM);
    float ia[8], oa[8], ua[8], xw[8], fc[8];
#pragma unroll
    for (int j = 0; j < 8; ++j) {
        ia[j] = bf2f(xi[j]); oa[j] = bf2f(xo[j]);
        ua[j] = bf2f(xu[j]); xw[j] = bf2f(xf[j]);
        fc[j] = 0.0f;
    }
    int4   ci = *(const int4*)&cidx[n * KCH];
    float4 cm = *(const float4*)&cmask[n * KCH];
    const int   cia[4] = {ci.x, ci.y, ci.z, ci.w};
    const float cma[4] = {cm.x, cm.y, cm.z, cm.w};
#pragma unroll
    for (int k = 0; k < KCH; ++k) {
        const float m = cma[k];
        if (m != 0.0f) {                       // wave-uniform branch
            const unsigned short* zr = Z + (size_t)cia[k] * 4 * HDIM + j8;
            us8 zi = *(const us8*)zr;
            us8 zo = *(const us8*)(zr + HDIM);
            us8 zu = *(const us8*)(zr + 2 * HDIM);
            us8 zf = *(const us8*)(zr + 3 * HDIM);
            const float* cpr = c_prev + (size_t)cia[k] * HDIM + j8;
            float4 ca = *(const float4*)cpr;
            float4 cb = *(const float4*)(cpr + 4);
            const float cp[8] = {ca.x, ca.y, ca.z, ca.w, cb.x, cb.y, cb.z, cb.w};
#pragma unroll
            for (int j = 0; j < 8; ++j) {
                ia[j] += m * bf2f(zi[j]);
                oa[j] += m * bf2f(zo[j]);
                ua[j] += m * bf2f(zu[j]);
                fc[j] += sigf(xw[j] + m * bf2f(zf[j])) * m * cp[j];
            }
        }
    }
    float cv[8], hv[8];
#pragma unroll
    for (int j = 0; j < 8; ++j) {
        cv[j] = sigf(ia[j]) * ftanh(ua[j]) + fc[j];
        hv[j] = sigf(oa[j]) * ftanh(cv[j]);
    }
    if (LAST) {
        float4 h0 = make_float4(hv[0], hv[1], hv[2], hv[3]);
        float4 h1 = make_float4(hv[4], hv[5], hv[6], hv[7]);
        *(float4*)(h_out + (size_t)n * HDIM + j8)     = h0;
        *(float4*)(h_out + (size_t)n * HDIM + j8 + 4) = h1;
    } else {
        float4 c0v = make_float4(cv[0], cv[1], cv[2], cv[3]);
        float4 c1v = make_float4(cv[4], cv[5], cv[6], cv[7]);
        *(float4*)(c_new + (size_t)n * HDIM + j8)     = c0v;
        *(float4*)(c_new + (size_t)n * HDIM + j8 + 4) = c1v;
        us8 hb;
#pragma unroll
        for (int j = 0; j < 8; ++j) hb[j] = f2bf(hv[j]);
        *(us8*)(hb_new + (size_t)n * HDIM + j8) = hb;
    }
}

// leaf: fc = 0, no children
__global__ __launch_bounds__(256) void gateleaf_k(
    const unsigned short* __restrict__ iouxW,
    float* __restrict__ c_new, unsigned short* __restrict__ hb_new)
{
    int t  = blockIdx.x * 256 + threadIdx.x;
    int n  = t >> 6;
    int j8 = (t & 63) << 3;
    const unsigned short* xr = iouxW + (size_t)n * 4 * HDIM + j8;
    us8 xi = *(const us8*)xr;
    us8 xo = *(const us8*)(xr + HDIM);
    us8 xu = *(const us8*)(xr + 2 * HDIM);
    float cv[8], hv[8];
#pragma unroll
    for (int j = 0; j < 8; ++j) {
        cv[j] = sigf(bf2f(xi[j])) * ftanh(bf2f(xu[j]));
        hv[j] = sigf(bf2f(xo[j])) * ftanh(cv[j]);
    }
    float4 c0v = make_float4(cv[0], cv[1], cv[2], cv[3]);
    float4 c1v = make_float4(cv[4], cv[5], cv[6], cv[7]);
    *(float4*)(c_new + (size_t)n * HDIM + j8)     = c0v;
    *(float4*)(c_new + (size_t)n * HDIM + j8 + 4) = c1v;
    us8 hb;
#pragma unroll
    for (int j = 0; j < 8; ++j) hb[j] = f2bf(hv[j]);
    *(us8*)(hb_new + (size_t)n * HDIM + j8) = hb;
}

extern "C" void kernel_launch(void* const* d_in, const int* in_sizes, int n_in,
                              void* d_out, int out_size, void* d_ws, size_t ws_size,
                              hipStream_t stream)
{
    const int*   vocab_ix   = (const int*)d_in[0];     // [L,N]
    const int*   child_idx  = (const int*)d_in[1];     // [L,N,K]
    const float* token_mask = (const float*)d_in[2];   // [L,N]
    const float* child_mask = (const float*)d_in[3];   // [L,N,K]
    const float* embed      = (const float*)d_in[4];   // [V,E] f32
    const float* W_iou      = (const float*)d_in[5];   // [E,3H]
    const float* U_iou      = (const float*)d_in[6];   // [H,3H]
    const float* b_iou      = (const float*)d_in[7];   // [3H]
    const float* W_f        = (const float*)d_in[8];   // [E,H]
    const float* U_f        = (const float*)d_in[9];   // [H,H]
    const float* b_f        = (const float*)d_in[10];  // [H]
    float* out = (float*)d_out;                        // [N,H] level-0 h

    // ---- workspace layout (~217 MB; ws is 256 MiB) ----
    float* ws = (float*)d_ws;
    float* c0 = ws;                                    // [N,H] f32
    float* c1 = c0 + (size_t)NN * HDIM;                // [N,H] f32
    unsigned short* usb   = (unsigned short*)(c1 + (size_t)NN * HDIM);
    unsigned short* hb0   = usb;                                // [N,H] bf16
    unsigned short* hb1   = hb0 + (size_t)NN * HDIM;            // [N,H] bf16
    unsigned short* iouxW = hb1 + (size_t)NN * HDIM;            // [3N,4H] bf16 (3-level batch)
    unsigned short* Z     = iouxW + (size_t)3 * NN * 4 * HDIM;  // [N,4H] bf16
    unsigned short* AbatA = Z + (size_t)NN * 4 * HDIM;          // [3N,EPAD] bf16 (levels 3..5)
    unsigned short* AbatB = AbatA + (size_t)3 * NN * EPAD;      // [3N,EPAD] bf16 (levels 0..2)
    unsigned short* WtALL = AbatB + (size_t)3 * NN * EPAD;      // [4H,EPAD] bf16
    unsigned short* UtALL = WtALL + (size_t)4 * HDIM * EPAD;    // [4H,H] bf16

    dim3 blk(256);

    // ---- converts (every launch; ws is re-poisoned); 2 launches ----
    gconv2_k<<<dim3(6 * NN * (EPAD / 8) / 256), blk, 0, stream>>>(
        embed, vocab_ix, token_mask, AbatA);
    wconvall_k<<<dim3((WCS0 + WCS1 + WCS2 + WCS3) / 256), blk, 0, stream>>>(
        W_iou, W_f, U_iou, U_f, WtALL, UtALL);

    unsigned short* bbuf[2] = { hb0, hb1 };
    float*          cbuf[2] = { c0,  c1  };

    const int ew_blocks = NN * HDIM / 8 / 256;   // 2048

    // Batch A: levels 3..5 (rows l-3), before the recurrence.
    // grid (8 n-groups, 192 m-tiles), NCHUNK=2 (measured optimum r6/r11)
    mgemm_k<1, 2><<<dim3(8, 3 * NN / BM), blk, 0, stream>>>(
        AbatA, WtALL, b_iou, b_f, iouxW, 4 * HDIM, EPAD);

    for (int l = LVLS - 1; l >= 0; --l) {
        const int p = (LVLS - 1 - l);            // 0..5
        unsigned short* hb_new  = bbuf[p & 1];
        float*          c_new   = cbuf[p & 1];
        unsigned short* hb_prev = bbuf[(p & 1) ^ 1];
        float*          c_prev  = cbuf[(p & 1) ^ 1];
        const int*   cix = child_idx  + (size_t)l * NN * KCH;
        const float* cm  = child_mask + (size_t)l * NN * KCH;
        const unsigned short* ix_l =
            iouxW + (size_t)((l >= 3) ? (l - 3) : l) * NN * 4 * HDIM;

        if (l == LVLS - 1) {
            gateleaf_k<<<dim3(ew_blocks), blk, 0, stream>>>(ix_l, c_new, hb_new);
        } else {
            // Z = h_prev @ [U_iou | U_f]   [8192 x 2048 x 512]
            // grid (16 n-tiles, 64 m-tiles) NCHUNK=1 (r7-measured best for Z)
            mgemm_k<0, 1><<<dim3(16, NN / BM), blk, 0, stream>>>(
                hb_prev, UtALL, nullptr, nullptr, Z, 4 * HDIM, HDIM);

            if (l == 0) {
                gatefc_k<true><<<dim3(ew_blocks), blk, 0, stream>>>(
                    ix_l, Z, cix, cm, c_prev, nullptr, nullptr, out);
            } else {
                gatefc_k<false><<<dim3(ew_blocks), blk, 0, stream>>>(
                    ix_l, Z, cix, cm, c_prev, c_new, hb_new, nullptr);
            }
        }

        // After level 3 is consumed, overwrite iouxW with batch B (levels 0..2).
        if (l == 3) {
            mgemm_k<1, 2><<<dim3(8, 3 * NN / BM), blk, 0, stream>>>(
                AbatB, WtALL, b_iou, b_f, iouxW, 4 * HDIM, EPAD);
        }
    }
}